// Round 5
// baseline (155.967 us; speedup 1.0000x reference)
//
#include <hip/hip_runtime.h>
#include <hip/hip_bf16.h>
#include <math.h>

#define BS   32
#define IC   64
#define OC   64
#define HH   128
#define WW   128
#define BANK 256
#define ADDR 64
#define WELEM (OC*IC*9)

// xbf padded layout: [b][130 rows][8 g][132 cols][8 ic] bf16 (borders zeroed)
#define XROW  (8 * 132 * 8)          // shorts per row = 8448
#define XSAMP (130 * XROW)

typedef short short8 __attribute__((ext_vector_type(8)));
typedef float f32x16 __attribute__((ext_vector_type(16)));

__device__ __forceinline__ short f2bf(float f) {
    unsigned u = __builtin_bit_cast(unsigned, f);
    unsigned r = (u + 0x7FFFu + ((u >> 16) & 1u)) >> 16;
    return (short)r;
}

typedef __attribute__((address_space(3))) unsigned int lds_u32;
typedef const __attribute__((address_space(1))) unsigned int g_u32;
__device__ __forceinline__ void gload16(const short* g, short* l) {
    __builtin_amdgcn_global_load_lds((g_u32*)g, (lds_u32*)l, 16, 0, 0);
}

// ---------------- kernel 1: sel_w = softmax(w_addr @ aspace^T) --------------
__global__ __launch_bounds__(BANK) void k_selw(const float* __restrict__ w_addr,
                                               const float* __restrict__ aspace,
                                               float* __restrict__ sel_w) {
    int b = blockIdx.x;
    int n = threadIdx.x;
    const float* wa = w_addr + b * ADDR;
    const float* as = aspace + n * ADDR;
    float dot = 0.f;
#pragma unroll
    for (int k = 0; k < ADDR; ++k) dot = fmaf(wa[k], as[k], dot);

    __shared__ float red[BANK];
    red[n] = dot; __syncthreads();
    for (int s = BANK / 2; s > 0; s >>= 1) {
        if (n < s) red[n] = fmaxf(red[n], red[n + s]);
        __syncthreads();
    }
    float m = red[0]; __syncthreads();
    float e = expf(dot - m);
    red[n] = e; __syncthreads();
    for (int s = BANK / 2; s > 0; s >>= 1) {
        if (n < s) red[n] += red[n + s];
        __syncthreads();
    }
    sel_w[b * BANK + n] = e / red[0];
}

// ---------------- kernel 2: bias[b][o] = softmax(b_addr@aspace^T) @ b_bank --
__global__ __launch_bounds__(BANK) void k_bias(const float* __restrict__ b_addr,
                                               const float* __restrict__ aspace,
                                               const float* __restrict__ b_bank,
                                               float* __restrict__ bias) {
    int bo = blockIdx.x;
    int n  = threadIdx.x;
    const float* ba = b_addr + (size_t)bo * ADDR;
    const float* as = aspace + n * ADDR;
    float dot = 0.f;
#pragma unroll
    for (int k = 0; k < ADDR; ++k) dot = fmaf(ba[k], as[k], dot);

    __shared__ float red[BANK];
    red[n] = dot; __syncthreads();
    for (int s = BANK / 2; s > 0; s >>= 1) {
        if (n < s) red[n] = fmaxf(red[n], red[n + s]);
        __syncthreads();
    }
    float m = red[0]; __syncthreads();
    float e = expf(dot - m);
    red[n] = e; __syncthreads();
    for (int s = BANK / 2; s > 0; s >>= 1) {
        if (n < s) red[n] += red[n + s];
        __syncthreads();
    }
    float denom = red[0]; __syncthreads();
    red[n] = e * b_bank[n]; __syncthreads();
    for (int s = BANK / 2; s > 0; s >>= 1) {
        if (n < s) red[n] += red[n + s];
        __syncthreads();
    }
    if (n == 0) bias[bo] = red[0] / denom;
}

// ---------------- kernel 3: weight mix -> bf16, MFMA-fragment layout --------
// wmb[b][tap(9)][icg(8)][oc(64)][ic8(8)]  (bf16)
__global__ __launch_bounds__(256) void k_wmix(const float* __restrict__ sel_w,
                                              const float* __restrict__ w_bank,
                                              __hip_bfloat16* __restrict__ wmb) {
    __shared__ float s_red[4 * 32 * 64];   // [chunk][b][jl] = 32 KB

    int tid = threadIdx.x;
    int jl  = tid & 63;
    int c   = tid >> 6;
    int jb  = blockIdx.x * 64 + jl;

    int n0 = __builtin_amdgcn_readfirstlane(c * 64);
    const float* selp = sel_w + n0;

    float wv[64];
#pragma unroll
    for (int n = 0; n < 64; ++n)
        wv[n] = w_bank[(size_t)(n0 + n) * WELEM + jb];

    float acc[BS];
#pragma unroll
    for (int b = 0; b < BS; ++b) acc[b] = 0.f;
#pragma unroll
    for (int b = 0; b < BS; ++b)
#pragma unroll
        for (int n = 0; n < 64; ++n)
            acc[b] = fmaf(selp[b * BANK + n], wv[n], acc[b]);

#pragma unroll
    for (int b = 0; b < BS; ++b)
        s_red[(c * 32 + b) * 64 + jl] = acc[b];
    __syncthreads();

    int B0  = (tid * 8) & 31;
    int jl2 = (tid * 8) >> 5;
    int j   = blockIdx.x * 64 + jl2;
    int o   = j / 576;
    int rem = j - o * 576;
    int i   = rem / 9;
    int tap = rem - i * 9;
    size_t base = ((size_t)tap * 8 + (i >> 3)) * 512 + (size_t)o * 8 + (i & 7);
#pragma unroll
    for (int u = 0; u < 8; ++u) {
        int b = B0 + u;
        float v = s_red[(0 * 32 + b) * 64 + jl2] + s_red[(1 * 32 + b) * 64 + jl2]
                + s_red[(2 * 32 + b) * 64 + jl2] + s_red[(3 * 32 + b) * 64 + jl2];
        short sv = f2bf(v);
        wmb[(size_t)b * (9 * 8 * 64 * 8) + base] = *reinterpret_cast<__hip_bfloat16*>(&sv);
    }
}

// ---------------- kernel 4: x NCHW f32 -> padded group-blocked bf16 ---------
// xbf[b][ry(130)][g(8)][col(132)][8]; ry=gy+1, col=gx+1; borders zeroed.
__global__ __launch_bounds__(256) void k_tr(const float* __restrict__ x,
                                            short* __restrict__ xbf) {
    int bid = blockIdx.x;              // b*130 + ry
    int b  = bid / 130;
    int ry = bid - b * 130;
    short* row = xbf + (size_t)b * XSAMP + (size_t)ry * XROW;
    int tid = threadIdx.x;
    short8 z = {0, 0, 0, 0, 0, 0, 0, 0};

    if (ry == 0 || ry == 129) {        // zero guard rows
        for (int u = tid; u < 1056; u += 256)
            *(short8*)(row + u * 8) = z;
        return;
    }
    int gy = ry - 1;
    const float* xb = x + ((size_t)b * IC * HH + gy) * WW;
    int icg = tid & 7;
    int px0 = (tid >> 3) * 4;

    float4 v[8];
#pragma unroll
    for (int e = 0; e < 8; ++e)
        v[e] = *(const float4*)&xb[(size_t)(icg * 8 + e) * HH * WW + px0];
#pragma unroll
    for (int p = 0; p < 4; ++p) {
        short8 s;
#pragma unroll
        for (int e = 0; e < 8; ++e)
            s[e] = f2bf(((const float*)&v[e])[p]);
        *(short8*)(row + ((size_t)icg * 132 + px0 + p + 1) * 8) = s;
    }
    if (tid < 32) {                    // zero guard cols 0,129 + pad 130,131
        int g = tid >> 2;
        int sel = tid & 3;
        int cz = (sel == 0) ? 0 : (128 + sel);   // 0,129,130,131
        *(short8*)(row + ((size_t)g * 132 + cz) * 8) = z;
    }
}

// ---------------- kernel 5: implicit-GEMM conv, global_load_lds + dbuf ------
// 2048 blocks = (b, 64 strips of 2 rows), XCD-swizzled; 512 thr / 8 waves.
// wave = (row wr, oc-half oh, px-half ph): 32 oc x 64 px -> 2 acc tiles.
// K: 4 chunks of 16 ic; double-buffered LDS; stage(cc+1) issued before
// MFMA(cc), barrier drain lands after MFMA -> latency hidden.
__global__ __launch_bounds__(512) void k_conv(const short* __restrict__ xbf,
                                              const short* __restrict__ wmb,
                                              const float* __restrict__ bias,
                                              float* __restrict__ out) {
    __shared__ short s_x[2][8704];     // 1088 units x 16B (1056 used + pad)
    __shared__ short s_w[2][9216];     // 1152 units x 16B
    __shared__ float s_bias[OC];

    int orig    = blockIdx.x;
    int logical = (orig & 7) * 256 + (orig >> 3);   // bijective (2048%8==0)
    int b   = logical >> 6;
    int y0  = (logical & 63) * 2;
    int tid = threadIdx.x;
    int wv  = tid >> 6;
    int lane = tid & 63;
    int h   = lane >> 5;
    int ln  = lane & 31;
    int wr  = wv & 1;
    int oh  = (wv >> 1) & 1;
    int ph  = wv >> 2;

    if (tid < OC) s_bias[tid] = bias[b * OC + tid];

    const short* xs   = xbf + (size_t)b * XSAMP + (size_t)y0 * XROW;
    const short* wmbs = wmb + (size_t)b * 36864;

    auto stage = [&](int cc, int bf) {
        // x chunk: rows ky=0..3 (xbf rows y0..y0+3), g-pair {2cc,2cc+1}:
        // 4 x 264 = 1056 linear units; 17 wave-instrs (pad lanes clamped)
        for (int i = wv; i < 17; i += 8) {
            int u  = i * 64 + lane;
            int uc = (u < 1056) ? u : 0;
            int ky  = uc / 264;
            int rem = uc - ky * 264;
            const short* g = xs + (size_t)ky * XROW + (size_t)(2 * cc * 132 + rem) * 8;
            gload16(g, &s_x[bf][i * 512]);
        }
        // w chunk: [tap9][g2][oc64][8] = 1152 linear units; 18 wave-instrs
        for (int j = wv; j < 18; j += 8) {
            int v   = j * 64 + lane;
            int tap = v >> 7;
            int wt  = v & 127;
            const short* g = wmbs + (size_t)((tap * 8 + 2 * cc) * 64 + wt) * 8;
            gload16(g, &s_w[bf][j * 512]);
        }
    };

    f32x16 acc[2];
    acc[0] = (f32x16)0.0f;
    acc[1] = (f32x16)0.0f;

    stage(0, 0);
    __syncthreads();                       // drain -> buf0 ready

    for (int cc = 0; cc < 4; ++cc) {
        int bf = cc & 1;
        if (cc < 3) stage(cc + 1, bf ^ 1); // in flight during MFMA
        const short8* xb8 = (const short8*)s_x[bf];
        const short8* wb8 = (const short8*)s_w[bf];
#pragma unroll
        for (int ky = 0; ky < 3; ++ky) {
#pragma unroll
            for (int kx = 0; kx < 3; ++kx) {
                short8 a = wb8[((ky * 3 + kx) * 2 + h) * 64 + oh * 32 + ln];
#pragma unroll
                for (int nt = 0; nt < 2; ++nt) {
                    short8 bb = xb8[((wr + ky) * 2 + h) * 132 + ph * 64 + nt * 32 + ln + kx];
                    acc[nt] = __builtin_amdgcn_mfma_f32_32x32x16_bf16(a, bb, acc[nt], 0, 0, 0);
                }
            }
        }
        __syncthreads();                   // drain stage(cc+1) + reader fence
    }

    // epilogue: C/D layout col=lane&31, row=(r&3)+8*(r>>2)+4*h
    int y = y0 + wr;
    float* ob = out + (size_t)b * OC * HH * WW;
#pragma unroll
    for (int nt = 0; nt < 2; ++nt) {
#pragma unroll
        for (int r = 0; r < 16; ++r) {
            int oc = oh * 32 + (r & 3) + 8 * (r >> 2) + 4 * h;
            int px = ph * 64 + nt * 32 + ln;
            ob[((size_t)oc * HH + y) * WW + px] = acc[nt][r] + s_bias[oc];
        }
    }
}

// ---------------------------------------------------------------------------
extern "C" void kernel_launch(void* const* d_in, const int* in_sizes, int n_in,
                              void* d_out, int out_size, void* d_ws, size_t ws_size,
                              hipStream_t stream) {
    const float* x      = (const float*)d_in[0];
    const float* w_addr = (const float*)d_in[1];
    const float* b_addr = (const float*)d_in[2];
    const float* w_bank = (const float*)d_in[3];
    const float* b_bank = (const float*)d_in[4];
    const float* aspace = (const float*)d_in[5];
    float* out = (float*)d_out;

    char* ws = (char*)d_ws;
    float*          sel_w = (float*)ws;                     // 32768 B
    float*          bias  = (float*)(ws + 32768);           //  8192 B
    __hip_bfloat16* wmb   = (__hip_bfloat16*)(ws + 40960);  // 2359296 B
    short*          xbf   = (short*)(ws + 40960 + 2359296); // 70287360 B

    k_selw<<<BS, BANK, 0, stream>>>(w_addr, aspace, sel_w);
    k_bias<<<BS * OC, BANK, 0, stream>>>(b_addr, aspace, b_bank, bias);
    k_wmix<<<WELEM / 64, 256, 0, stream>>>(sel_w, w_bank, wmb);
    k_tr<<<BS * 130, 256, 0, stream>>>(x, xbf);
    k_conv<<<BS * 64, 512, 0, stream>>>(xbf, (const short*)wmb, bias, out);
}

// Round 7
// 137.278 us; speedup vs baseline: 1.1361x; 1.1361x over previous
//
#include <hip/hip_runtime.h>
#include <hip/hip_bf16.h>
#include <math.h>

#define BS   32
#define IC   64
#define OC   64
#define HH   128
#define WW   128
#define BANK 256
#define ADDR 64
#define WELEM (OC*IC*9)
#define PLANE (HH*WW)

typedef short short8 __attribute__((ext_vector_type(8)));
typedef float f32x16 __attribute__((ext_vector_type(16)));

__device__ __forceinline__ short f2bf(float f) {
    unsigned u = __builtin_bit_cast(unsigned, f);
    unsigned r = (u + 0x7FFFu + ((u >> 16) & 1u)) >> 16;
    return (short)r;
}

__device__ __forceinline__ unsigned pack_bf2(float lo, float hi) {
    unsigned ul = __builtin_bit_cast(unsigned, lo);
    unsigned uh = __builtin_bit_cast(unsigned, hi);
    unsigned rl = (ul + 0x7FFFu + ((ul >> 16) & 1u)) >> 16;
    unsigned rh = (uh + 0x7FFFu + ((uh >> 16) & 1u)) & 0xFFFF0000u;
    return rh | (rl & 0xFFFFu);
}

// ---------------- kernel 1: sel_w = softmax(w_addr @ aspace^T) --------------
__global__ __launch_bounds__(BANK) void k_selw(const float* __restrict__ w_addr,
                                               const float* __restrict__ aspace,
                                               float* __restrict__ sel_w) {
    int b = blockIdx.x;
    int n = threadIdx.x;
    const float* wa = w_addr + b * ADDR;
    const float* as = aspace + n * ADDR;
    float dot = 0.f;
#pragma unroll
    for (int k = 0; k < ADDR; ++k) dot = fmaf(wa[k], as[k], dot);

    __shared__ float red[BANK];
    red[n] = dot; __syncthreads();
    for (int s = BANK / 2; s > 0; s >>= 1) {
        if (n < s) red[n] = fmaxf(red[n], red[n + s]);
        __syncthreads();
    }
    float m = red[0]; __syncthreads();
    float e = expf(dot - m);
    red[n] = e; __syncthreads();
    for (int s = BANK / 2; s > 0; s >>= 1) {
        if (n < s) red[n] += red[n + s];
        __syncthreads();
    }
    sel_w[b * BANK + n] = e / red[0];
}

// ---------------- kernel 2: bias[b][o] = softmax(b_addr@aspace^T) @ b_bank --
__global__ __launch_bounds__(BANK) void k_bias(const float* __restrict__ b_addr,
                                               const float* __restrict__ aspace,
                                               const float* __restrict__ b_bank,
                                               float* __restrict__ bias) {
    int bo = blockIdx.x;
    int n  = threadIdx.x;
    const float* ba = b_addr + (size_t)bo * ADDR;
    const float* as = aspace + n * ADDR;
    float dot = 0.f;
#pragma unroll
    for (int k = 0; k < ADDR; ++k) dot = fmaf(ba[k], as[k], dot);

    __shared__ float red[BANK];
    red[n] = dot; __syncthreads();
    for (int s = BANK / 2; s > 0; s >>= 1) {
        if (n < s) red[n] = fmaxf(red[n], red[n + s]);
        __syncthreads();
    }
    float m = red[0]; __syncthreads();
    float e = expf(dot - m);
    red[n] = e; __syncthreads();
    for (int s = BANK / 2; s > 0; s >>= 1) {
        if (n < s) red[n] += red[n + s];
        __syncthreads();
    }
    float denom = red[0]; __syncthreads();
    red[n] = e * b_bank[n]; __syncthreads();
    for (int s = BANK / 2; s > 0; s >>= 1) {
        if (n < s) red[n] += red[n + s];
        __syncthreads();
    }
    if (n == 0) bias[bo] = red[0] / denom;
}

// ---------------- kernel 3: weight mix -> bf16, MFMA-fragment layout --------
// wmb[b][tap(9)][icg(8)][oc(64)][ic8(8)]  (bf16)
__global__ __launch_bounds__(256) void k_wmix(const float* __restrict__ sel_w,
                                              const float* __restrict__ w_bank,
                                              __hip_bfloat16* __restrict__ wmb) {
    __shared__ float s_red[4 * 32 * 64];   // [chunk][b][jl] = 32 KB

    int tid = threadIdx.x;
    int jl  = tid & 63;
    int c   = tid >> 6;
    int jb  = blockIdx.x * 64 + jl;

    int n0 = __builtin_amdgcn_readfirstlane(c * 64);
    const float* selp = sel_w + n0;

    float wv[64];
#pragma unroll
    for (int n = 0; n < 64; ++n)
        wv[n] = w_bank[(size_t)(n0 + n) * WELEM + jb];

    float acc[BS];
#pragma unroll
    for (int b = 0; b < BS; ++b) acc[b] = 0.f;
#pragma unroll
    for (int b = 0; b < BS; ++b)
#pragma unroll
        for (int n = 0; n < 64; ++n)
            acc[b] = fmaf(selp[b * BANK + n], wv[n], acc[b]);

#pragma unroll
    for (int b = 0; b < BS; ++b)
        s_red[(c * 32 + b) * 64 + jl] = acc[b];
    __syncthreads();

    int B0  = (tid * 8) & 31;
    int jl2 = (tid * 8) >> 5;
    int j   = blockIdx.x * 64 + jl2;
    int o   = j / 576;
    int rem = j - o * 576;
    int i   = rem / 9;
    int tap = rem - i * 9;
    size_t base = ((size_t)tap * 8 + (i >> 3)) * 512 + (size_t)o * 8 + (i & 7);
#pragma unroll
    for (int u = 0; u < 8; ++u) {
        int b = B0 + u;
        float v = s_red[(0 * 32 + b) * 64 + jl2] + s_red[(1 * 32 + b) * 64 + jl2]
                + s_red[(2 * 32 + b) * 64 + jl2] + s_red[(3 * 32 + b) * 64 + jl2];
        short sv = f2bf(v);
        wmb[(size_t)b * (9 * 8 * 64 * 8) + base] = *reinterpret_cast<__hip_bfloat16*>(&sv);
    }
}

// ---------------- kernel 4: FUSED implicit-GEMM conv (reads fp32 NCHW) ------
// 2048 blocks = (b, 64 strips of 2 rows), XCD-swizzled; 512 thr / 8 waves.
// wave = (row wr, oc-half oh, px-half ph): 32 oc x 64 px -> 2 acc tiles.
// K: 4 chunks of 16 ic. Double-buffered LDS, T14 order:
//   { issue loads(cc+1); MFMA(buf cc); convert+write buf^1 (vmcnt drains
//     here, after MFMA); barrier }  -> HBM latency hidden under MFMA.
__global__ __launch_bounds__(512, 4) void k_conv(const float* __restrict__ x,
                                                 const short* __restrict__ wmb,
                                                 const float* __restrict__ bias,
                                                 float* __restrict__ out) {
    __shared__ short s_x[2][4 * 2 * 132 * 8];  // [buf][ky][g][col][ic8] 16896 B x2
    __shared__ short s_w[2][9 * 2 * 64 * 8];   // [buf][tap][g][oc][ic8] 18432 B x2
    __shared__ float s_bias[OC];

    int orig    = blockIdx.x;
    int logical = (orig & 7) * 256 + (orig >> 3);   // bijective (2048%8==0)
    int b    = logical >> 6;
    int y0   = (logical & 63) * 2;
    int tid  = threadIdx.x;
    int lane = tid & 63;
    int wv   = tid >> 6;
    int h    = lane >> 5;
    int ln   = lane & 31;
    int wr   = wv & 1;
    int oh   = (wv >> 1) & 1;
    int ph   = wv >> 2;

    if (tid < OC) s_bias[tid] = bias[b * OC + tid];
    // halo cols 0 and 129 are structurally zero: zero once, never rewritten
    if (tid < 32) {
        int bf   = tid >> 4;
        int kg   = (tid >> 1) & 7;       // ky*2+g
        int col  = (tid & 1) ? 129 : 0;
        *(short8*)&s_x[bf][(kg * 132 + col) * 8] = (short8){0,0,0,0,0,0,0,0};
    }

    const float* xb   = x + (size_t)b * IC * PLANE;
    const short* wmbs = wmb + (size_t)b * 36864;

    // ---- staging descriptors ----
    // x units (per chunk): u = k*512+tid, k=0..1; u -> (ky=u>>8, icp=(u>>5)&7, colq=u&31)
    // loads ic-pair (2icp, 2icp+1) float4 at (gy=y0-1+ky, gx=colq*4)
    int x_ky[2], x_icp[2], x_colq[2]; bool x_ok[2];
#pragma unroll
    for (int k = 0; k < 2; ++k) {
        int u = k * 512 + tid;
        x_colq[k] = u & 31;
        x_icp[k]  = (u >> 5) & 7;
        x_ky[k]   = u >> 8;
        int gy = y0 - 1 + x_ky[k];
        x_ok[k] = ((unsigned)gy < (unsigned)HH);
    }
    // w units: v = k*512+tid, k=0..2, v<1152 -> (tap=v>>7, g=(v>>6)&1, oc=v&63)
    bool w_val[3]; int w_tap[3], w_g[3], w_oc[3];
#pragma unroll
    for (int k = 0; k < 3; ++k) {
        int v = k * 512 + tid;
        w_val[k] = (v < 1152);
        int vv = w_val[k] ? v : 0;
        w_tap[k] = vv >> 7; w_g[k] = (vv >> 6) & 1; w_oc[k] = vv & 63;
    }

    float4 xlo[2], xhi[2];
    short8 wreg[3];

    auto LOAD = [&](int cc) {
#pragma unroll
        for (int k = 0; k < 2; ++k) {
            if (x_ok[k]) {
                const float* p = xb + (size_t)(cc * 16 + 2 * x_icp[k]) * PLANE
                               + (y0 - 1 + x_ky[k]) * WW + x_colq[k] * 4;
                xlo[k] = *(const float4*)p;
                xhi[k] = *(const float4*)(p + PLANE);
            } else {
                xlo[k] = make_float4(0.f, 0.f, 0.f, 0.f);
                xhi[k] = make_float4(0.f, 0.f, 0.f, 0.f);
            }
        }
#pragma unroll
        for (int k = 0; k < 3; ++k)
            if (w_val[k])
                wreg[k] = *(const short8*)(wmbs +
                    (size_t)((w_tap[k] * 8 + 2 * cc + w_g[k]) * 64 + w_oc[k]) * 8);
    };
    auto STORE = [&](int bf) {
        unsigned* sx32 = (unsigned*)s_x[bf];
#pragma unroll
        for (int k = 0; k < 2; ++k) {
            int g  = x_icp[k] >> 2;
            int pi = x_icp[k] & 3;
            int rowbase = (x_ky[k] * 2 + g) * 132;
#pragma unroll
            for (int j = 0; j < 4; ++j) {
                unsigned pk = pack_bf2(((const float*)&xlo[k])[j],
                                       ((const float*)&xhi[k])[j]);
                int col = x_colq[k] * 4 + 1 + j;
                sx32[((rowbase + col) * 8 + pi * 2) >> 1] = pk;
            }
        }
#pragma unroll
        for (int k = 0; k < 3; ++k)
            if (w_val[k])
                *(short8*)&s_w[bf][((w_tap[k] * 2 + w_g[k]) * 64 + w_oc[k]) * 8] = wreg[k];
    };

    f32x16 acc[2];
    acc[0] = (f32x16)0.0f;
    acc[1] = (f32x16)0.0f;

    LOAD(0);
    STORE(0);
    __syncthreads();

#pragma unroll
    for (int cc = 0; cc < 4; ++cc) {
        int bf = cc & 1;
        if (cc < 3) LOAD(cc + 1);          // in flight during MFMA
        const short8* xb8 = (const short8*)s_x[bf];
        const short8* wb8 = (const short8*)s_w[bf];
#pragma unroll
        for (int ky = 0; ky < 3; ++ky) {
#pragma unroll
            for (int kx = 0; kx < 3; ++kx) {
                short8 a = wb8[((ky * 3 + kx) * 2 + h) * 64 + oh * 32 + ln];
#pragma unroll
                for (int nt = 0; nt < 2; ++nt) {
                    short8 bb = xb8[((wr + ky) * 2 + h) * 132 + ph * 64 + nt * 32 + ln + kx];
                    acc[nt] = __builtin_amdgcn_mfma_f32_32x32x16_bf16(a, bb, acc[nt], 0, 0, 0);
                }
            }
        }
        if (cc < 3) STORE(bf ^ 1);         // vmcnt drain lands after MFMA
        __syncthreads();
    }

    // epilogue: C/D layout col=lane&31, row=(r&3)+8*(r>>2)+4*h
    int y = y0 + wr;
    float* ob = out + (size_t)b * OC * PLANE;
#pragma unroll
    for (int nt = 0; nt < 2; ++nt) {
#pragma unroll
        for (int r = 0; r < 16; ++r) {
            int oc = oh * 32 + (r & 3) + 8 * (r >> 2) + 4 * h;
            int px = ph * 64 + nt * 32 + ln;
            ob[((size_t)oc * HH + y) * WW + px] = acc[nt][r] + s_bias[oc];
        }
    }
}

// ---------------------------------------------------------------------------
extern "C" void kernel_launch(void* const* d_in, const int* in_sizes, int n_in,
                              void* d_out, int out_size, void* d_ws, size_t ws_size,
                              hipStream_t stream) {
    const float* x      = (const float*)d_in[0];
    const float* w_addr = (const float*)d_in[1];
    const float* b_addr = (const float*)d_in[2];
    const float* w_bank = (const float*)d_in[3];
    const float* b_bank = (const float*)d_in[4];
    const float* aspace = (const float*)d_in[5];
    float* out = (float*)d_out;

    char* ws = (char*)d_ws;
    float*          sel_w = (float*)ws;                     // 32768 B
    float*          bias  = (float*)(ws + 32768);           //  8192 B
    __hip_bfloat16* wmb   = (__hip_bfloat16*)(ws + 40960);  // 2359296 B

    k_selw<<<BS, BANK, 0, stream>>>(w_addr, aspace, sel_w);
    k_bias<<<BS * OC, BANK, 0, stream>>>(b_addr, aspace, b_bank, bias);
    k_wmix<<<WELEM / 64, 256, 0, stream>>>(sel_w, w_bank, wmb);
    k_conv<<<BS * 64, 512, 0, stream>>>(x, (const short*)wmb, bias, out);
}

// Round 8
// 133.188 us; speedup vs baseline: 1.1710x; 1.0307x over previous
//
#include <hip/hip_runtime.h>
#include <hip/hip_bf16.h>
#include <math.h>

#define BS   32
#define IC   64
#define OC   64
#define HH   128
#define WW   128
#define BANK 256
#define ADDR 64
#define WELEM (OC*IC*9)
#define PLANE (HH*WW)

typedef short short8 __attribute__((ext_vector_type(8)));
typedef float f32x16 __attribute__((ext_vector_type(16)));

__device__ __forceinline__ short f2bf(float f) {
    unsigned u = __builtin_bit_cast(unsigned, f);
    unsigned r = (u + 0x7FFFu + ((u >> 16) & 1u)) >> 16;
    return (short)r;
}

// ---------------- kernel 1: sel_w = softmax(w_addr @ aspace^T) --------------
__global__ __launch_bounds__(BANK) void k_selw(const float* __restrict__ w_addr,
                                               const float* __restrict__ aspace,
                                               float* __restrict__ sel_w) {
    int b = blockIdx.x;
    int n = threadIdx.x;
    const float* wa = w_addr + b * ADDR;
    const float* as = aspace + n * ADDR;
    float dot = 0.f;
#pragma unroll
    for (int k = 0; k < ADDR; ++k) dot = fmaf(wa[k], as[k], dot);

    __shared__ float red[BANK];
    red[n] = dot; __syncthreads();
    for (int s = BANK / 2; s > 0; s >>= 1) {
        if (n < s) red[n] = fmaxf(red[n], red[n + s]);
        __syncthreads();
    }
    float m = red[0]; __syncthreads();
    float e = expf(dot - m);
    red[n] = e; __syncthreads();
    for (int s = BANK / 2; s > 0; s >>= 1) {
        if (n < s) red[n] += red[n + s];
        __syncthreads();
    }
    sel_w[b * BANK + n] = e / red[0];
}

// ---------------- kernel 2: bias[b][o] = softmax(b_addr@aspace^T) @ b_bank --
__global__ __launch_bounds__(BANK) void k_bias(const float* __restrict__ b_addr,
                                               const float* __restrict__ aspace,
                                               const float* __restrict__ b_bank,
                                               float* __restrict__ bias) {
    int bo = blockIdx.x;
    int n  = threadIdx.x;
    const float* ba = b_addr + (size_t)bo * ADDR;
    const float* as = aspace + n * ADDR;
    float dot = 0.f;
#pragma unroll
    for (int k = 0; k < ADDR; ++k) dot = fmaf(ba[k], as[k], dot);

    __shared__ float red[BANK];
    red[n] = dot; __syncthreads();
    for (int s = BANK / 2; s > 0; s >>= 1) {
        if (n < s) red[n] = fmaxf(red[n], red[n + s]);
        __syncthreads();
    }
    float m = red[0]; __syncthreads();
    float e = expf(dot - m);
    red[n] = e; __syncthreads();
    for (int s = BANK / 2; s > 0; s >>= 1) {
        if (n < s) red[n] += red[n + s];
        __syncthreads();
    }
    float denom = red[0]; __syncthreads();
    red[n] = e * b_bank[n]; __syncthreads();
    for (int s = BANK / 2; s > 0; s >>= 1) {
        if (n < s) red[n] += red[n + s];
        __syncthreads();
    }
    if (n == 0) bias[bo] = red[0] / denom;
}

// ---------------- kernel 3: weight mix -> bf16, MFMA-fragment layout --------
// wmb[b][tap(9)][icg(8)][oc(64)][ic8(8)]  (bf16)
__global__ __launch_bounds__(256) void k_wmix(const float* __restrict__ sel_w,
                                              const float* __restrict__ w_bank,
                                              __hip_bfloat16* __restrict__ wmb) {
    __shared__ float s_red[4 * 32 * 64];   // [chunk][b][jl] = 32 KB

    int tid = threadIdx.x;
    int jl  = tid & 63;
    int c   = tid >> 6;
    int jb  = blockIdx.x * 64 + jl;

    int n0 = __builtin_amdgcn_readfirstlane(c * 64);
    const float* selp = sel_w + n0;

    float wv[64];
#pragma unroll
    for (int n = 0; n < 64; ++n)
        wv[n] = w_bank[(size_t)(n0 + n) * WELEM + jb];

    float acc[BS];
#pragma unroll
    for (int b = 0; b < BS; ++b) acc[b] = 0.f;
#pragma unroll
    for (int b = 0; b < BS; ++b)
#pragma unroll
        for (int n = 0; n < 64; ++n)
            acc[b] = fmaf(selp[b * BANK + n], wv[n], acc[b]);

#pragma unroll
    for (int b = 0; b < BS; ++b)
        s_red[(c * 32 + b) * 64 + jl] = acc[b];
    __syncthreads();

    int B0  = (tid * 8) & 31;
    int jl2 = (tid * 8) >> 5;
    int j   = blockIdx.x * 64 + jl2;
    int o   = j / 576;
    int rem = j - o * 576;
    int i   = rem / 9;
    int tap = rem - i * 9;
    size_t base = ((size_t)tap * 8 + (i >> 3)) * 512 + (size_t)o * 8 + (i & 7);
#pragma unroll
    for (int u = 0; u < 8; ++u) {
        int b = B0 + u;
        float v = s_red[(0 * 32 + b) * 64 + jl2] + s_red[(1 * 32 + b) * 64 + jl2]
                + s_red[(2 * 32 + b) * 64 + jl2] + s_red[(3 * 32 + b) * 64 + jl2];
        short sv = f2bf(v);
        wmb[(size_t)b * (9 * 8 * 64 * 8) + base] = *reinterpret_cast<__hip_bfloat16*>(&sv);
    }
}

// ---------------- kernel 4: FUSED implicit-GEMM conv (reads fp32 NCHW) ------
// 2048 blocks = (b, 64 strips of 2 rows), XCD-swizzled; 512 thr / 8 waves.
// wave = (row wr, oc-half oh, px-half ph): 32 oc x 64 px -> 2 acc tiles.
// K: 4 chunks of 16 ic. Double-buffered LDS, one barrier per chunk:
//   { issue loads(cc+1); MFMA(buf cc); STORE(buf^1); barrier }.
// x staging: thread owns full [col][ic8] units (8 plane-strided scalar loads,
// lane-contiguous gx -> 256B/instr coalesced) -> ONE ds_write_b128 per unit,
// lane-contiguous -> conflict-free (fixes R7's 16-way ds_write_b32 conflict).
__global__ __launch_bounds__(512, 4) void k_conv(const float* __restrict__ x,
                                                 const short* __restrict__ wmb,
                                                 const float* __restrict__ bias,
                                                 float* __restrict__ out) {
    __shared__ short s_x[2][4 * 2 * 132 * 8];  // [buf][ky][g][col(132)][ic8]
    __shared__ short s_w[2][9 * 2 * 64 * 8];   // [buf][tap][g][oc][ic8]
    __shared__ float s_bias[OC];

    int orig    = blockIdx.x;
    int logical = (orig & 7) * 256 + (orig >> 3);   // bijective (2048%8==0)
    int b    = logical >> 6;
    int y0   = (logical & 63) * 2;
    int tid  = threadIdx.x;
    int lane = tid & 63;
    int wv   = tid >> 6;
    int h    = lane >> 5;
    int ln   = lane & 31;
    int wr   = wv & 1;
    int oh   = (wv >> 1) & 1;
    int ph   = wv >> 2;

    if (tid < OC) s_bias[tid] = bias[b * OC + tid];
    // halo cols 0 and 129 are structurally zero: zero once, never rewritten
    if (tid < 32) {
        int bf   = tid >> 4;
        int kg   = (tid >> 1) & 7;       // ky*2+g
        int col  = (tid & 1) ? 129 : 0;
        *(short8*)&s_x[bf][(kg * 132 + col) * 8] = (short8){0,0,0,0,0,0,0,0};
    }

    const float* xb   = x + (size_t)b * IC * PLANE;
    const short* wmbs = wmb + (size_t)b * 36864;

    // ---- x staging descriptors: unit u = k*512+tid, u<1024 ----
    // u -> (ky=u>>8, g=(u>>7)&1, cx=u&127); col=cx+1; 8 ic loads per unit.
    int x_goff[2], x_lds[2]; bool x_ok[2]; int x_g[2];
#pragma unroll
    for (int k = 0; k < 2; ++k) {
        int u  = k * 512 + tid;
        int ky = u >> 8;
        int g  = (u >> 7) & 1;
        int cx = u & 127;
        int gy = y0 - 1 + ky;
        x_ok[k]   = ((unsigned)gy < (unsigned)HH);
        x_g[k]    = g;
        x_goff[k] = gy * WW + cx;
        x_lds[k]  = ((ky * 2 + g) * 132 + cx + 1) * 8;
    }
    // w units: v = k*512+tid, k=0..2, v<1152 -> (tap=v>>7, g=(v>>6)&1, oc=v&63)
    bool w_val[3]; int w_tap[3], w_g[3], w_oc[3];
#pragma unroll
    for (int k = 0; k < 3; ++k) {
        int v = k * 512 + tid;
        w_val[k] = (v < 1152);
        int vv = w_val[k] ? v : 0;
        w_tap[k] = vv >> 7; w_g[k] = (vv >> 6) & 1; w_oc[k] = vv & 63;
    }

    float  xr[2][8];
    short8 wreg[3];

    auto LOAD = [&](int cc) {
#pragma unroll
        for (int k = 0; k < 2; ++k) {
            if (x_ok[k]) {
                const float* p = xb + (size_t)(cc * 16 + x_g[k] * 8) * PLANE + x_goff[k];
#pragma unroll
                for (int e = 0; e < 8; ++e) xr[k][e] = p[(size_t)e * PLANE];
            } else {
#pragma unroll
                for (int e = 0; e < 8; ++e) xr[k][e] = 0.f;
            }
        }
#pragma unroll
        for (int k = 0; k < 3; ++k)
            if (w_val[k])
                wreg[k] = *(const short8*)(wmbs +
                    (size_t)((w_tap[k] * 8 + 2 * cc + w_g[k]) * 64 + w_oc[k]) * 8);
    };
    auto STORE = [&](int bf) {
#pragma unroll
        for (int k = 0; k < 2; ++k) {
            short8 s;
#pragma unroll
            for (int e = 0; e < 8; ++e) s[e] = f2bf(xr[k][e]);
            *(short8*)&s_x[bf][x_lds[k]] = s;           // b128, lane-contiguous
        }
#pragma unroll
        for (int k = 0; k < 3; ++k)
            if (w_val[k])
                *(short8*)&s_w[bf][((w_tap[k] * 2 + w_g[k]) * 64 + w_oc[k]) * 8] = wreg[k];
    };

    f32x16 acc[2];
    acc[0] = (f32x16)0.0f;
    acc[1] = (f32x16)0.0f;

    LOAD(0);
    STORE(0);
    __syncthreads();

#pragma unroll
    for (int cc = 0; cc < 4; ++cc) {
        int bf = cc & 1;
        if (cc < 3) LOAD(cc + 1);          // in flight during MFMA
        const short8* xb8 = (const short8*)s_x[bf];
        const short8* wb8 = (const short8*)s_w[bf];
#pragma unroll
        for (int ky = 0; ky < 3; ++ky) {
#pragma unroll
            for (int kx = 0; kx < 3; ++kx) {
                short8 a = wb8[((ky * 3 + kx) * 2 + h) * 64 + oh * 32 + ln];
#pragma unroll
                for (int nt = 0; nt < 2; ++nt) {
                    short8 bb = xb8[((wr + ky) * 2 + h) * 132 + ph * 64 + nt * 32 + ln + kx];
                    acc[nt] = __builtin_amdgcn_mfma_f32_32x32x16_bf16(a, bb, acc[nt], 0, 0, 0);
                }
            }
        }
        if (cc < 3) STORE(bf ^ 1);         // vmcnt drain lands after MFMA
        __syncthreads();
    }

    // epilogue: C/D layout col=lane&31, row=(r&3)+8*(r>>2)+4*h
    int y = y0 + wr;
    float* ob = out + (size_t)b * OC * PLANE;
#pragma unroll
    for (int nt = 0; nt < 2; ++nt) {
#pragma unroll
        for (int r = 0; r < 16; ++r) {
            int oc = oh * 32 + (r & 3) + 8 * (r >> 2) + 4 * h;
            int px = ph * 64 + nt * 32 + ln;
            ob[((size_t)oc * HH + y) * WW + px] = acc[nt][r] + s_bias[oc];
        }
    }
}

// ---------------------------------------------------------------------------
extern "C" void kernel_launch(void* const* d_in, const int* in_sizes, int n_in,
                              void* d_out, int out_size, void* d_ws, size_t ws_size,
                              hipStream_t stream) {
    const float* x      = (const float*)d_in[0];
    const float* w_addr = (const float*)d_in[1];
    const float* b_addr = (const float*)d_in[2];
    const float* w_bank = (const float*)d_in[3];
    const float* b_bank = (const float*)d_in[4];
    const float* aspace = (const float*)d_in[5];
    float* out = (float*)d_out;

    char* ws = (char*)d_ws;
    float*          sel_w = (float*)ws;                     // 32768 B
    float*          bias  = (float*)(ws + 32768);           //  8192 B
    __hip_bfloat16* wmb   = (__hip_bfloat16*)(ws + 40960);  // 2359296 B

    k_selw<<<BS, BANK, 0, stream>>>(w_addr, aspace, sel_w);
    k_bias<<<BS * OC, BANK, 0, stream>>>(b_addr, aspace, b_bank, bias);
    k_wmix<<<WELEM / 64, 256, 0, stream>>>(sel_w, w_bank, wmb);
    k_conv<<<BS * 64, 512, 0, stream>>>(x, (const short*)wmb, bias, out);
}

// Round 9
// 129.047 us; speedup vs baseline: 1.2086x; 1.0321x over previous
//
#include <hip/hip_runtime.h>
#include <hip/hip_bf16.h>
#include <math.h>

#define BS   32
#define IC   64
#define OC   64
#define HH   128
#define WW   128
#define BANK 256
#define ADDR 64
#define WELEM (OC*IC*9)
#define PLANE (HH*WW)

typedef short short8 __attribute__((ext_vector_type(8)));
typedef float f32x16 __attribute__((ext_vector_type(16)));

__device__ __forceinline__ short f2bf(float f) {
    unsigned u = __builtin_bit_cast(unsigned, f);
    unsigned r = (u + 0x7FFFu + ((u >> 16) & 1u)) >> 16;
    return (short)r;
}

typedef __attribute__((address_space(3))) unsigned int lds_u32;
typedef const __attribute__((address_space(1))) unsigned int g_u32;
__device__ __forceinline__ void gload16(const short* g, short* l) {
    __builtin_amdgcn_global_load_lds((g_u32*)g, (lds_u32*)l, 16, 0, 0);
}

// ---------------- kernel 1: sel_w = softmax(w_addr @ aspace^T) --------------
__global__ __launch_bounds__(BANK) void k_selw(const float* __restrict__ w_addr,
                                               const float* __restrict__ aspace,
                                               float* __restrict__ sel_w) {
    int b = blockIdx.x;
    int n = threadIdx.x;
    const float* wa = w_addr + b * ADDR;
    const float* as = aspace + n * ADDR;
    float dot = 0.f;
#pragma unroll
    for (int k = 0; k < ADDR; ++k) dot = fmaf(wa[k], as[k], dot);

    __shared__ float red[BANK];
    red[n] = dot; __syncthreads();
    for (int s = BANK / 2; s > 0; s >>= 1) {
        if (n < s) red[n] = fmaxf(red[n], red[n + s]);
        __syncthreads();
    }
    float m = red[0]; __syncthreads();
    float e = expf(dot - m);
    red[n] = e; __syncthreads();
    for (int s = BANK / 2; s > 0; s >>= 1) {
        if (n < s) red[n] += red[n + s];
        __syncthreads();
    }
    sel_w[b * BANK + n] = e / red[0];
}

// ---------------- kernel 2: bias[b][o] = softmax(b_addr@aspace^T) @ b_bank --
__global__ __launch_bounds__(BANK) void k_bias(const float* __restrict__ b_addr,
                                               const float* __restrict__ aspace,
                                               const float* __restrict__ b_bank,
                                               float* __restrict__ bias) {
    int bo = blockIdx.x;
    int n  = threadIdx.x;
    const float* ba = b_addr + (size_t)bo * ADDR;
    const float* as = aspace + n * ADDR;
    float dot = 0.f;
#pragma unroll
    for (int k = 0; k < ADDR; ++k) dot = fmaf(ba[k], as[k], dot);

    __shared__ float red[BANK];
    red[n] = dot; __syncthreads();
    for (int s = BANK / 2; s > 0; s >>= 1) {
        if (n < s) red[n] = fmaxf(red[n], red[n + s]);
        __syncthreads();
    }
    float m = red[0]; __syncthreads();
    float e = expf(dot - m);
    red[n] = e; __syncthreads();
    for (int s = BANK / 2; s > 0; s >>= 1) {
        if (n < s) red[n] += red[n + s];
        __syncthreads();
    }
    float denom = red[0]; __syncthreads();
    red[n] = e * b_bank[n]; __syncthreads();
    for (int s = BANK / 2; s > 0; s >>= 1) {
        if (n < s) red[n] += red[n + s];
        __syncthreads();
    }
    if (n == 0) bias[bo] = red[0] / denom;
}

// ---------------- kernel 3: weight mix -> bf16, MFMA-fragment layout --------
// wmb[b][tap(9)][icg(8)][oc(64)][ic8(8)]  (bf16)
__global__ __launch_bounds__(256) void k_wmix(const float* __restrict__ sel_w,
                                              const float* __restrict__ w_bank,
                                              __hip_bfloat16* __restrict__ wmb) {
    __shared__ float s_red[4 * 32 * 64];   // [chunk][b][jl] = 32 KB

    int tid = threadIdx.x;
    int jl  = tid & 63;
    int c   = tid >> 6;
    int jb  = blockIdx.x * 64 + jl;

    int n0 = __builtin_amdgcn_readfirstlane(c * 64);
    const float* selp = sel_w + n0;

    float wv[64];
#pragma unroll
    for (int n = 0; n < 64; ++n)
        wv[n] = w_bank[(size_t)(n0 + n) * WELEM + jb];

    float acc[BS];
#pragma unroll
    for (int b = 0; b < BS; ++b) acc[b] = 0.f;
#pragma unroll
    for (int b = 0; b < BS; ++b)
#pragma unroll
        for (int n = 0; n < 64; ++n)
            acc[b] = fmaf(selp[b * BANK + n], wv[n], acc[b]);

#pragma unroll
    for (int b = 0; b < BS; ++b)
        s_red[(c * 32 + b) * 64 + jl] = acc[b];
    __syncthreads();

    int B0  = (tid * 8) & 31;
    int jl2 = (tid * 8) >> 5;
    int j   = blockIdx.x * 64 + jl2;
    int o   = j / 576;
    int rem = j - o * 576;
    int i   = rem / 9;
    int tap = rem - i * 9;
    size_t base = ((size_t)tap * 8 + (i >> 3)) * 512 + (size_t)o * 8 + (i & 7);
#pragma unroll
    for (int u = 0; u < 8; ++u) {
        int b = B0 + u;
        float v = s_red[(0 * 32 + b) * 64 + jl2] + s_red[(1 * 32 + b) * 64 + jl2]
                + s_red[(2 * 32 + b) * 64 + jl2] + s_red[(3 * 32 + b) * 64 + jl2];
        short sv = f2bf(v);
        wmb[(size_t)b * (9 * 8 * 64 * 8) + base] = *reinterpret_cast<__hip_bfloat16*>(&sv);
    }
}

// ---------------- kernel 4: FUSED implicit-GEMM conv (reads fp32 NCHW) ------
// 2048 blocks = (b, 64 strips of 2 rows), XCD-swizzled; 512 thr / 8 waves.
// wave = (row wr, oc-half oh, px-half ph): 32 oc x 64 px -> 2 acc tiles.
// K: 4 chunks of 16 ic. Double-buffered LDS, one barrier per chunk.
// x staging: reg (8 plane-strided scalars -> 1 ds_write_b128, conflict-free).
// w staging: global_load_lds (contiguous 1KB slices, zero reg pressure).
__global__ __launch_bounds__(512, 2) void k_conv(const float* __restrict__ x,
                                                 const short* __restrict__ wmb,
                                                 const float* __restrict__ bias,
                                                 float* __restrict__ out) {
    __shared__ short s_x[2][4 * 2 * 132 * 8];  // [buf][ky][g][col(132)][ic8]
    __shared__ short s_w[2][9 * 2 * 64 * 8];   // [buf][tap][g][oc][ic8]
    __shared__ float s_bias[OC];

    int orig    = blockIdx.x;
    int logical = (orig & 7) * 256 + (orig >> 3);   // bijective (2048%8==0)
    int b    = logical >> 6;
    int y0   = (logical & 63) * 2;
    int tid  = threadIdx.x;
    int lane = tid & 63;
    int wv   = tid >> 6;
    int h    = lane >> 5;
    int ln   = lane & 31;
    int wr   = wv & 1;
    int oh   = (wv >> 1) & 1;
    int ph   = wv >> 2;

    if (tid < OC) s_bias[tid] = bias[b * OC + tid];
    // halo cols 0 and 129 are structurally zero: zero once, never rewritten
    if (tid < 32) {
        int bf   = tid >> 4;
        int kg   = (tid >> 1) & 7;       // ky*2+g
        int col  = (tid & 1) ? 129 : 0;
        *(short8*)&s_x[bf][(kg * 132 + col) * 8] = (short8){0,0,0,0,0,0,0,0};
    }

    const float* xb   = x + (size_t)b * IC * PLANE;
    const short* wmbs = wmb + (size_t)b * 36864;

    // ---- x staging descriptors: unit u = k*512+tid, u<1024 ----
    // u -> (ky=u>>8, g=(u>>7)&1, cx=u&127); col=cx+1; 8 ic loads per unit.
    int x_goff[2], x_lds[2]; bool x_ok[2]; int x_g[2];
#pragma unroll
    for (int k = 0; k < 2; ++k) {
        int u  = k * 512 + tid;
        int ky = u >> 8;
        int g  = (u >> 7) & 1;
        int cx = u & 127;
        int gy = y0 - 1 + ky;
        x_ok[k]   = ((unsigned)gy < (unsigned)HH);
        x_g[k]    = g;
        x_goff[k] = gy * WW + cx;
        x_lds[k]  = ((ky * 2 + g) * 132 + cx + 1) * 8;
    }

    float xr[2][8];

    auto LOADX = [&](int cc) {
#pragma unroll
        for (int k = 0; k < 2; ++k) {
            if (x_ok[k]) {
                const float* p = xb + (size_t)(cc * 16 + x_g[k] * 8) * PLANE + x_goff[k];
#pragma unroll
                for (int e = 0; e < 8; ++e) xr[k][e] = p[(size_t)e * PLANE];
            } else {
#pragma unroll
                for (int e = 0; e < 8; ++e) xr[k][e] = 0.f;
            }
        }
    };
    // w: 18 slices (tap,g); each slice 64 lanes x 16B contiguous, linear dest
    auto STAGEW = [&](int cc, int bf) {
        for (int s = wv; s < 18; s += 8) {
            int tap = s >> 1, g = s & 1;
            const short* gsrc = wmbs + (size_t)((tap * 8 + 2 * cc + g) * 64 + lane) * 8;
            gload16(gsrc, &s_w[bf][((tap * 2 + g) * 64) * 8]);
        }
    };
    auto STOREX = [&](int bf) {
#pragma unroll
        for (int k = 0; k < 2; ++k) {
            short8 s;
#pragma unroll
            for (int e = 0; e < 8; ++e) s[e] = f2bf(xr[k][e]);
            *(short8*)&s_x[bf][x_lds[k]] = s;           // b128, lane-contiguous
        }
    };

    f32x16 acc[2];
    acc[0] = (f32x16)0.0f;
    acc[1] = (f32x16)0.0f;

    LOADX(0);
    STAGEW(0, 0);
    STOREX(0);
    __syncthreads();

#pragma unroll
    for (int cc = 0; cc < 4; ++cc) {
        int bf = cc & 1;
        if (cc < 3) {
            LOADX(cc + 1);                 // x -> regs, in flight during MFMA
            STAGEW(cc + 1, bf ^ 1);        // w -> LDS direct, in flight
            __builtin_amdgcn_sched_barrier(0);   // forbid sinking loads below
        }
        const short8* xb8 = (const short8*)s_x[bf];
        const short8* wb8 = (const short8*)s_w[bf];
#pragma unroll
        for (int ky = 0; ky < 3; ++ky) {
#pragma unroll
            for (int kx = 0; kx < 3; ++kx) {
                short8 a = wb8[((ky * 3 + kx) * 2 + h) * 64 + oh * 32 + ln];
#pragma unroll
                for (int nt = 0; nt < 2; ++nt) {
                    short8 bb = xb8[((wr + ky) * 2 + h) * 132 + ph * 64 + nt * 32 + ln + kx];
                    acc[nt] = __builtin_amdgcn_mfma_f32_32x32x16_bf16(a, bb, acc[nt], 0, 0, 0);
                }
            }
        }
        if (cc < 3) STOREX(bf ^ 1);        // waits xr; vmcnt drain after MFMA
        __syncthreads();
    }

    // epilogue: C/D layout col=lane&31, row=(r&3)+8*(r>>2)+4*h
    int y = y0 + wr;
    float* ob = out + (size_t)b * OC * PLANE;
#pragma unroll
    for (int nt = 0; nt < 2; ++nt) {
#pragma unroll
        for (int r = 0; r < 16; ++r) {
            int oc = oh * 32 + (r & 3) + 8 * (r >> 2) + 4 * h;
            int px = ph * 64 + nt * 32 + ln;
            ob[((size_t)oc * HH + y) * WW + px] = acc[nt][r] + s_bias[oc];
        }
    }
}

// ---------------------------------------------------------------------------
extern "C" void kernel_launch(void* const* d_in, const int* in_sizes, int n_in,
                              void* d_out, int out_size, void* d_ws, size_t ws_size,
                              hipStream_t stream) {
    const float* x      = (const float*)d_in[0];
    const float* w_addr = (const float*)d_in[1];
    const float* b_addr = (const float*)d_in[2];
    const float* w_bank = (const float*)d_in[3];
    const float* b_bank = (const float*)d_in[4];
    const float* aspace = (const float*)d_in[5];
    float* out = (float*)d_out;

    char* ws = (char*)d_ws;
    float*          sel_w = (float*)ws;                     // 32768 B
    float*          bias  = (float*)(ws + 32768);           //  8192 B
    __hip_bfloat16* wmb   = (__hip_bfloat16*)(ws + 40960);  // 2359296 B

    k_selw<<<BS, BANK, 0, stream>>>(w_addr, aspace, sel_w);
    k_bias<<<BS * OC, BANK, 0, stream>>>(b_addr, aspace, b_bank, bias);
    k_wmix<<<WELEM / 64, 256, 0, stream>>>(sel_w, w_bank, wmb);
    k_conv<<<BS * 64, 512, 0, stream>>>(x, (const short*)wmb, bias, out);
}